// Round 3
// baseline (240.321 us; speedup 1.0000x reference)
//
#include <hip/hip_runtime.h>
#include <math.h>

// Problem constants (from reference)
#define B_ 16
#define T_ 12
#define F_ 32
#define N_ 500
#define L_ 3
#define K_ 2
#define INV_N1 (1.0f / 501.0f)

// ---------------------------------------------------------------------------
// Per-layer fused kernel: {fold Wc = gcn_w[li] @ gate_w (scaled 1/(N+1)),
// bc = gcn_b@gate_w + gate_b} in LDS, column-sum over nodes, then per-node
// g = sigmoid(bc + (colsum + row) . Wc).
// block = one (b,t): 512 threads, thread tid <-> node tid. grid = B_*T_.
// ---------------------------------------------------------------------------
__global__ __launch_bounds__(512) void gcn_fused_kernel(
                                 const float* __restrict__ x,
                                 const float* __restrict__ gcn_w,
                                 const float* __restrict__ gcn_b,
                                 const float* __restrict__ gate_w,
                                 const float* __restrict__ gate_b,
                                 int li, float* __restrict__ g) {
    __shared__ float sWc[F_ * F_];
    __shared__ float sbc[F_];
    __shared__ float scs[F_];
    __shared__ float wpart[8][F_];
    const int bt = blockIdx.x;
    const int tid = threadIdx.x;

    // fold W1@W2 (scaled) into LDS
    for (int idx = tid; idx < F_ * F_; idx += 512) {
        int fi = idx >> 5, fo = idx & 31;
        float a = 0.f;
#pragma unroll
        for (int m = 0; m < F_; ++m)
            a += gcn_w[(li * F_ + fi) * F_ + m] * gate_w[m * F_ + fo];
        sWc[idx] = a * INV_N1;
    }
    if (tid < F_) {
        float a = gate_b[tid];
#pragma unroll
        for (int m = 0; m < F_; ++m)
            a += gcn_b[li * F_ + m] * gate_w[m * F_ + tid];
        sbc[tid] = a;
    }

    // load this node's feature row (threads 500..511 contribute zeros)
    const int n = tid;
    float row[F_];
    if (n < N_) {
        const float* xr = x + (size_t)bt * F_ * N_ + n;
#pragma unroll
        for (int fi = 0; fi < F_; ++fi) row[fi] = xr[fi * N_];
    } else {
#pragma unroll
        for (int fi = 0; fi < F_; ++fi) row[fi] = 0.f;
    }

    // wave-wide butterfly sum per feature; lane 0 of each wave stashes partial
    const int lane = tid & 63;
    const int wv = tid >> 6;
#pragma unroll
    for (int fi = 0; fi < F_; ++fi) {
        float v = row[fi];
#pragma unroll
        for (int off = 32; off >= 1; off >>= 1) v += __shfl_xor(v, off, 64);
        if (lane == 0) wpart[wv][fi] = v;
    }
    __syncthreads();
    if (tid < F_) {
        float a = 0.f;
#pragma unroll
        for (int w = 0; w < 8; ++w) a += wpart[w][tid];
        scs[tid] = a;
    }
    __syncthreads();

    if (n < N_) {
        float acc[F_];
#pragma unroll
        for (int fo = 0; fo < F_; ++fo) acc[fo] = sbc[fo];
#pragma unroll
        for (int fi = 0; fi < F_; ++fi) {
            float xv = row[fi] + scs[fi];
#pragma unroll
            for (int fo = 0; fo < F_; ++fo) acc[fo] += xv * sWc[fi * F_ + fo];
        }
        float* gr = g + (size_t)bt * F_ * N_ + n;
#pragma unroll
        for (int fo = 0; fo < F_; ++fo)
            gr[fo * N_] = 1.f / (1.f + __expf(-acc[fo]));
    }
}

// ---------------------------------------------------------------------------
// Causal dilated conv (K=2) + bias + relu + residual; stash t==T-1 into res.
// out[t][fo] = relu(cb[fo] + sum_fi g[t-dil][fi]*w[fo][fi][0] + g[t][fi]*w[fo][fi][1])
// x_out = out + x_in (x_in/x_out may alias: same-thread same-address only).
// grid: B_*T_*4 blocks x 128 threads
// ---------------------------------------------------------------------------
__global__ __launch_bounds__(128) void conv_kernel(
                            const float* __restrict__ g,
                            const float* __restrict__ conv_w,
                            const float* __restrict__ conv_b,
                            int li, int dil,
                            const float* x_in,
                            float* x_out,
                            float* __restrict__ res_store) {
    __shared__ float sW[F_ * F_ * K_];
    __shared__ float sB[F_];
    const float* wsrc = conv_w + (size_t)li * F_ * F_ * K_;
    for (int idx = threadIdx.x; idx < F_ * F_ * K_; idx += 128) sW[idx] = wsrc[idx];
    if (threadIdx.x < F_) sB[threadIdx.x] = conv_b[li * F_ + threadIdx.x];
    __syncthreads();

    const int bt = blockIdx.x >> 2;
    const int t = bt % T_;
    const int b = bt / T_;
    const int n = (blockIdx.x & 3) * 128 + threadIdx.x;
    if (n >= N_) return;

    float gcur[F_], gprev[F_];
    const float* gc = g + (size_t)bt * F_ * N_ + n;
#pragma unroll
    for (int fi = 0; fi < F_; ++fi) gcur[fi] = gc[fi * N_];
    if (t >= dil) {
        const float* gp = g + (size_t)(bt - dil) * F_ * N_ + n;
#pragma unroll
        for (int fi = 0; fi < F_; ++fi) gprev[fi] = gp[fi * N_];
    } else {
#pragma unroll
        for (int fi = 0; fi < F_; ++fi) gprev[fi] = 0.f;
    }

    // residual row loaded before any store (x_in may alias x_out)
    float resv[F_];
    const float* xr = x_in + (size_t)bt * F_ * N_ + n;
#pragma unroll
    for (int fo = 0; fo < F_; ++fo) resv[fo] = xr[fo * N_];

    float* xo = x_out + (size_t)bt * F_ * N_ + n;
    const bool last = (t == T_ - 1);
    float* rs = res_store + (size_t)(b * N_ + n) * F_ * L_ + li;

#pragma unroll
    for (int fo = 0; fo < F_; ++fo) {
        float acc = sB[fo];
#pragma unroll
        for (int fi = 0; fi < F_; ++fi) {
            acc += gprev[fi] * sW[(fo * F_ + fi) * K_ + 0]
                 + gcur[fi]  * sW[(fo * F_ + fi) * K_ + 1];
        }
        float o = fmaxf(acc, 0.f);
        xo[fo * N_] = o + resv[fo];
        if (last) rs[fo * L_] = o;
    }
}

// ---------------------------------------------------------------------------
// Fused attention: scores (with the reference's reshape quirk), softmax over
// L, weighted combine. block = 192 threads = 2 output nodes x 3 scores x 32
// fo-lanes; grid = B_*N_/2 = 4000 blocks.
// score_orig(b,l,n) = sum_fo tanh(ba[fo] + sum_f res[b][n][f][l]*Wa[f][fo])*v[fo]
// output (b,n,l) takes score at flat j=n*3+l -> (l'=j/500, n'=j%500).
// ---------------------------------------------------------------------------
__global__ __launch_bounds__(192) void att_kernel(
                           const float* __restrict__ res_store,
                           const float* __restrict__ Wa,
                           const float* __restrict__ ba,
                           const float* __restrict__ v,
                           float* __restrict__ out) {
    __shared__ float sWa[F_ * F_];
    __shared__ float sScore[2][L_];
    const int tid = threadIdx.x;
    for (int idx = tid; idx < F_ * F_; idx += 192) sWa[idx] = Wa[idx];
    __syncthreads();

    const int pair = blockIdx.x;            // 0..3999
    const int b = pair / 250;
    const int base_n = (pair % 250) * 2;
    const int gIdx = tid >> 5;              // 0..5
    const int fo = tid & 31;
    const int o = gIdx / 3, l = gIdx % 3;
    const int n = base_n + o;
    const int j = n * 3 + l;                // flat reshape index
    const int lp = j / N_, np = j % N_;

    const float vv = v[fo];
    const float* r = res_store + (size_t)(b * N_ + np) * F_ * L_ + lp;
    float acc = ba[fo];
#pragma unroll
    for (int f = 0; f < F_; ++f) acc += r[f * L_] * sWa[f * F_ + fo];
    float s = tanhf(acc) * vv;
#pragma unroll
    for (int off = 16; off >= 1; off >>= 1) s += __shfl_xor(s, off, 64);
    if (fo == 0) sScore[o][l] = s;
    __syncthreads();

    if (tid < 64) {
        const int oo = tid >> 5, f = tid & 31;
        const int nn = base_n + oo;
        const float s0 = sScore[oo][0], s1 = sScore[oo][1], s2 = sScore[oo][2];
        const float m = fmaxf(fmaxf(s0, s1), s2);
        const float e0 = __expf(s0 - m), e1 = __expf(s1 - m), e2 = __expf(s2 - m);
        const float inv = 1.f / (e0 + e1 + e2);
        const float* rr = res_store + (size_t)(b * N_ + nn) * F_ * L_ + (size_t)f * L_;
        out[(size_t)(b * N_ + nn) * F_ + f] =
            (e0 * rr[0] + e1 * rr[1] + e2 * rr[2]) * inv;
    }
}

// ---------------------------------------------------------------------------
extern "C" void kernel_launch(void* const* d_in, const int* in_sizes, int n_in,
                              void* d_out, int out_size, void* d_ws, size_t ws_size,
                              hipStream_t stream) {
    const float* x0      = (const float*)d_in[0];   // node_embeddings (B,T,F,N)
    const float* conv_w  = (const float*)d_in[4];   // (L,F,F,1,K)
    const float* conv_b  = (const float*)d_in[5];   // (L,F)
    const float* gcn_w   = (const float*)d_in[6];   // (L,F,F)
    const float* gcn_b   = (const float*)d_in[7];   // (L,F)
    const float* gate_w  = (const float*)d_in[8];   // (F,F)
    const float* gate_b  = (const float*)d_in[9];   // (F,)
    const float* att_Wa  = (const float*)d_in[10];  // (F,F)
    const float* att_ba  = (const float*)d_in[11];  // (F,)
    const float* att_v   = (const float*)d_in[12];  // (F,1)

    float* ws = (float*)d_ws;
    float* x         = ws;                   // B*T*F*N = 3,072,000
    float* g         = x + 3072000;          // 3,072,000
    float* res_store = g + 3072000;          // B*N*F*L = 768,000
    // total ~27.6 MB of workspace

    const int dils[3] = {1, 2, 4};
    const float* xin = x0;
    for (int li = 0; li < L_; ++li) {
        gcn_fused_kernel<<<B_ * T_, 512, 0, stream>>>(xin, gcn_w, gcn_b,
                                                      gate_w, gate_b, li, g);
        conv_kernel<<<B_ * T_ * 4, 128, 0, stream>>>(g, conv_w, conv_b, li,
                                                     dils[li], xin, x, res_store);
        xin = x;
    }

    att_kernel<<<(B_ * N_) / 2, 192, 0, stream>>>(res_store, att_Wa, att_ba,
                                                  att_v, (float*)d_out);
}

// Round 4
// 202.841 us; speedup vs baseline: 1.1848x; 1.1848x over previous
//
#include <hip/hip_runtime.h>
#include <math.h>

// Problem constants (from reference)
#define B_ 16
#define T_ 12
#define F_ 32
#define N_ 500
#define L_ 3
#define K_ 2
#define INV_N1 (1.0f / 501.0f)

__device__ __forceinline__ float sigmoidf_(float x) {
    return 1.f / (1.f + __expf(-x));
}

// ---------------------------------------------------------------------------
// Prep kernel. grid = B_*T_ (192) blocks x 256 threads.
// Per block bt: colsum0[bt][f] = sum_n x0[bt][f][n] (float4, butterfly over 8
// j-lanes); zero cs1/cs2 slices. Blocks 0..2 additionally fold
// Wc[li] = (gcn_w[li] @ gate_w) / (N+1), bc[li] = gcn_b[li] @ gate_w + gate_b.
// ---------------------------------------------------------------------------
__global__ __launch_bounds__(256) void prep_kernel(
        const float* __restrict__ x0,
        const float* __restrict__ gcn_w, const float* __restrict__ gcn_b,
        const float* __restrict__ gate_w, const float* __restrict__ gate_b,
        float* __restrict__ Wc, float* __restrict__ bc,
        float* __restrict__ cs0, float* __restrict__ cs1,
        float* __restrict__ cs2) {
    const int bt = blockIdx.x;
    const int tid = threadIdx.x;

    if (tid < F_) {  // zero next-layer colsum accumulators
        cs1[bt * F_ + tid] = 0.f;
        cs2[bt * F_ + tid] = 0.f;
    }

    // colsum of x0 for layer 0
    const int f = tid >> 3, j = tid & 7;
    const float4* row = (const float4*)(x0 + ((size_t)bt * F_ + f) * N_);
    float s = 0.f;
    for (int j4 = j; j4 < 125; j4 += 8) {
        float4 v = row[j4];
        s += v.x + v.y + v.z + v.w;
    }
    s += __shfl_xor(s, 1, 64);
    s += __shfl_xor(s, 2, 64);
    s += __shfl_xor(s, 4, 64);
    if (j == 0) cs0[bt * F_ + f] = s;

    // weight folds (blocks 0..2)
    if (bt < L_) {
        const int li = bt;
        for (int idx = tid; idx < F_ * F_; idx += 256) {
            int fi = idx >> 5, fo = idx & 31;
            float a = 0.f;
#pragma unroll
            for (int m = 0; m < F_; ++m)
                a += gcn_w[(li * F_ + fi) * F_ + m] * gate_w[m * F_ + fo];
            Wc[li * F_ * F_ + idx] = a * INV_N1;
        }
        if (tid < F_) {
            float a = gate_b[tid];
#pragma unroll
            for (int m = 0; m < F_; ++m)
                a += gcn_b[li * F_ + m] * gate_w[m * F_ + tid];
            bc[li * F_ + tid] = a;
        }
    }
}

// ---------------------------------------------------------------------------
// GCN+gate kernel. grid = B_*T_*4 (768) blocks x 512 threads.
// Block (bt, chunk of 128 nodes): stage x tile [32][128] via float4, compute
// g = sigmoid(base[fo] + row . Wc) with base = bc + colsum . Wc precomputed.
// Thread = (n = tid&127, q = tid>>7) computes 8 fo's.
// ---------------------------------------------------------------------------
__global__ __launch_bounds__(512) void gcn_kernel(
        const float* __restrict__ xin,
        const float* __restrict__ Wc, const float* __restrict__ bc,
        const float* __restrict__ cs, int li, float* __restrict__ g) {
    __shared__ __align__(16) float sx[F_][128];
    __shared__ __align__(16) float sWc[F_ * F_];
    __shared__ float sbase[F_];

    const int blk = blockIdx.x;
    const int bt = blk >> 2, c = blk & 3;
    const int nbase = c * 128;
    const int nb4 = (c == 3) ? 29 : 32;  // float4s per feature row in this chunk
    const int tid = threadIdx.x;

    // stage x tile (coalesced float4)
    for (int idx = tid; idx < F_ * nb4; idx += 512) {
        int f = idx / nb4, j4 = idx % nb4;
        float4 v = *(const float4*)(xin + ((size_t)bt * F_ + f) * N_ + nbase + 4 * j4);
        ((float4*)&sx[f][0])[j4] = v;
    }
    // stage folded weights
    for (int idx = tid; idx < 256; idx += 512)
        ((float4*)sWc)[idx] = ((const float4*)(Wc + li * F_ * F_))[idx];
    // base vector (32 threads; uses global Wc, no LDS dependency)
    if (tid < F_) {
        float a = bc[li * F_ + tid];
#pragma unroll
        for (int fi = 0; fi < F_; ++fi)
            a += cs[bt * F_ + fi] * Wc[li * F_ * F_ + fi * F_ + tid];
        sbase[tid] = a;
    }
    __syncthreads();

    const int n = tid & 127, q = tid >> 7;
    const int gn = nbase + n;
    if (gn < N_) {
        float acc[8];
#pragma unroll
        for (int jj = 0; jj < 8; ++jj) acc[jj] = sbase[q * 8 + jj];
#pragma unroll
        for (int fi = 0; fi < F_; ++fi) {
            float xv = sx[fi][n];
#pragma unroll
            for (int jj = 0; jj < 8; ++jj)
                acc[jj] += xv * sWc[fi * F_ + q * 8 + jj];
        }
#pragma unroll
        for (int jj = 0; jj < 8; ++jj)
            g[((size_t)bt * F_ + q * 8 + jj) * N_ + gn] = sigmoidf_(acc[jj]);
    }
}

// ---------------------------------------------------------------------------
// Conv kernel. grid = B_*T_*4 (768) blocks x 512 threads.
// Block (bt, chunk): stage gcur/gprev tiles [32][128] + weights in LDS.
// Thread (n, q) computes 8 fo's: o = relu(bias + sum_fi gprev*w0 + gcur*w1),
// xout = o + xin (residual, may alias), res stash at t==T-1, and (if do_cs)
// wave-butterfly + atomicAdd of colsum(xout) for the next layer.
// ---------------------------------------------------------------------------
__global__ __launch_bounds__(512) void conv_kernel(
        const float* __restrict__ g,
        const float* __restrict__ conv_w, const float* __restrict__ conv_b,
        int li, int dil,
        const float* xin, float* xout,
        float* __restrict__ resP, float* __restrict__ cs_next, int do_cs) {
    __shared__ __align__(16) float sgc[F_][128];
    __shared__ __align__(16) float sgp[F_][128];
    __shared__ __align__(16) float sW[F_ * F_ * K_];
    __shared__ float sB[F_];

    const int blk = blockIdx.x;
    const int bt = blk >> 2, c = blk & 3;
    const int t = bt % T_, b = bt / T_;
    const int nbase = c * 128;
    const int nb4 = (c == 3) ? 29 : 32;
    const int tid = threadIdx.x;

    // stage weights (2048 floats = 512 float4, one per thread)
    ((float4*)sW)[tid] = ((const float4*)(conv_w + (size_t)li * F_ * F_ * K_))[tid];
    if (tid < F_) sB[tid] = conv_b[li * F_ + tid];

    // stage gcur tile
    for (int idx = tid; idx < F_ * nb4; idx += 512) {
        int f = idx / nb4, j4 = idx % nb4;
        ((float4*)&sgc[f][0])[j4] =
            *(const float4*)(g + ((size_t)bt * F_ + f) * N_ + nbase + 4 * j4);
    }
    // stage gprev tile (zeros when t < dil)
    if (t >= dil) {
        for (int idx = tid; idx < F_ * nb4; idx += 512) {
            int f = idx / nb4, j4 = idx % nb4;
            ((float4*)&sgp[f][0])[j4] =
                *(const float4*)(g + ((size_t)(bt - dil) * F_ + f) * N_ + nbase + 4 * j4);
        }
    } else {
        for (int idx = tid; idx < F_ * nb4; idx += 512) {
            int f = idx / nb4, j4 = idx % nb4;
            ((float4*)&sgp[f][0])[j4] = make_float4(0.f, 0.f, 0.f, 0.f);
        }
    }
    __syncthreads();

    const int n = tid & 127, q = tid >> 7;
    const int gn = nbase + n;
    const bool valid = (gn < N_);

    float acc[8], xov[8];
#pragma unroll
    for (int jj = 0; jj < 8; ++jj) { acc[jj] = sB[q * 8 + jj]; xov[jj] = 0.f; }

    if (valid) {
#pragma unroll
        for (int fi = 0; fi < F_; ++fi) {
            float gp = sgp[fi][n], gc = sgc[fi][n];
#pragma unroll
            for (int jj = 0; jj < 8; ++jj) {
                const int fo = q * 8 + jj;
                acc[jj] += gp * sW[(fo * F_ + fi) * K_ + 0]
                         + gc * sW[(fo * F_ + fi) * K_ + 1];
            }
        }
#pragma unroll
        for (int jj = 0; jj < 8; ++jj) {
            const int fo = q * 8 + jj;
            float o = fmaxf(acc[jj], 0.f);
            float rv = xin[((size_t)bt * F_ + fo) * N_ + gn];
            float xo = o + rv;
            xout[((size_t)bt * F_ + fo) * N_ + gn] = xo;
            acc[jj] = o;   // keep relu output for res stash
            xov[jj] = xo;  // for colsum
        }
        if (t == T_ - 1) {
            float* rs = resP + ((size_t)(li * B_ + b) * N_ + gn) * F_ + q * 8;
#pragma unroll
            for (int jj = 0; jj < 8; ++jj) rs[jj] = acc[jj];
        }
    }

    // colsum of xout for next layer (all 512 threads participate; invalid = 0)
    if (do_cs) {
        const int lane = tid & 63;
#pragma unroll
        for (int jj = 0; jj < 8; ++jj) {
            float s = xov[jj];
#pragma unroll
            for (int off = 32; off >= 1; off >>= 1) s += __shfl_xor(s, off, 64);
            if (lane == 0) atomicAdd(&cs_next[bt * F_ + q * 8 + jj], s);
        }
    }
}

// ---------------------------------------------------------------------------
// Fused attention. grid = B_*N_/2 (4000) blocks x 192 threads.
// res layout resP[l][b][n][f] (f contiguous). Stage 1: 6 groups of 32 lanes
// compute score(b, l, n) with the reference's reshape quirk (j=n*3+l ->
// l'=j/500, n'=j%500). Stage 2: softmax over L + weighted combine.
// ---------------------------------------------------------------------------
__global__ __launch_bounds__(192) void att_kernel(
        const float* __restrict__ resP,
        const float* __restrict__ Wa, const float* __restrict__ ba,
        const float* __restrict__ v, float* __restrict__ out) {
    __shared__ __align__(16) float sWa[F_ * F_];
    __shared__ float sScore[2][L_];
    const int tid = threadIdx.x;
    for (int idx = tid; idx < F_ * F_; idx += 192) sWa[idx] = Wa[idx];
    __syncthreads();

    const int pair = blockIdx.x;
    const int b = pair / 250;
    const int base_n = (pair % 250) * 2;
    const int gIdx = tid >> 5;  // 0..5
    const int fo = tid & 31;
    const int o = gIdx / 3, l = gIdx % 3;
    const int n = base_n + o;
    const int j = n * 3 + l;
    const int lp = j / N_, np = j % N_;

    const float vv = v[fo];
    const float* r = resP + ((size_t)(lp * B_ + b) * N_ + np) * F_;
    float acc = ba[fo];
#pragma unroll
    for (int f = 0; f < F_; ++f) acc += r[f] * sWa[f * F_ + fo];
    float s = tanhf(acc) * vv;
#pragma unroll
    for (int off = 16; off >= 1; off >>= 1) s += __shfl_xor(s, off, 64);
    if (fo == 0) sScore[o][l] = s;
    __syncthreads();

    if (tid < 64) {
        const int oo = tid >> 5, f = tid & 31;
        const int nn = base_n + oo;
        const float s0 = sScore[oo][0], s1 = sScore[oo][1], s2 = sScore[oo][2];
        const float m = fmaxf(fmaxf(s0, s1), s2);
        const float e0 = __expf(s0 - m), e1 = __expf(s1 - m), e2 = __expf(s2 - m);
        const float inv = 1.f / (e0 + e1 + e2);
        const float r0 = resP[((size_t)(0 * B_ + b) * N_ + nn) * F_ + f];
        const float r1 = resP[((size_t)(1 * B_ + b) * N_ + nn) * F_ + f];
        const float r2 = resP[((size_t)(2 * B_ + b) * N_ + nn) * F_ + f];
        out[(size_t)(b * N_ + nn) * F_ + f] = (e0 * r0 + e1 * r1 + e2 * r2) * inv;
    }
}

// ---------------------------------------------------------------------------
extern "C" void kernel_launch(void* const* d_in, const int* in_sizes, int n_in,
                              void* d_out, int out_size, void* d_ws, size_t ws_size,
                              hipStream_t stream) {
    const float* x0      = (const float*)d_in[0];   // node_embeddings (B,T,F,N)
    const float* conv_w  = (const float*)d_in[4];   // (L,F,F,1,K)
    const float* conv_b  = (const float*)d_in[5];   // (L,F)
    const float* gcn_w   = (const float*)d_in[6];   // (L,F,F)
    const float* gcn_b   = (const float*)d_in[7];   // (L,F)
    const float* gate_w  = (const float*)d_in[8];   // (F,F)
    const float* gate_b  = (const float*)d_in[9];   // (F,)
    const float* att_Wa  = (const float*)d_in[10];  // (F,F)
    const float* att_ba  = (const float*)d_in[11];  // (F,)
    const float* att_v   = (const float*)d_in[12];  // (F,1)

    float* ws = (float*)d_ws;
    float* x    = ws;               // B*T*F*N = 3,072,000
    float* g    = x + 3072000;      // 3,072,000
    float* resP = g + 3072000;      // L*B*N*F = 768,000
    float* Wc   = resP + 768000;    // 3*32*32 = 3072
    float* bc   = Wc + 3072;        // 96
    float* cs0  = bc + 96;          // B*T*F = 6144
    float* cs1  = cs0 + 6144;       // 6144
    float* cs2  = cs1 + 6144;       // 6144
    // total ~27.8 MB

    prep_kernel<<<B_ * T_, 256, 0, stream>>>(x0, gcn_w, gcn_b, gate_w, gate_b,
                                             Wc, bc, cs0, cs1, cs2);

    gcn_kernel<<<B_ * T_ * 4, 512, 0, stream>>>(x0, Wc, bc, cs0, 0, g);
    conv_kernel<<<B_ * T_ * 4, 512, 0, stream>>>(g, conv_w, conv_b, 0, 1,
                                                 x0, x, resP, cs1, 1);
    gcn_kernel<<<B_ * T_ * 4, 512, 0, stream>>>(x, Wc, bc, cs1, 1, g);
    conv_kernel<<<B_ * T_ * 4, 512, 0, stream>>>(g, conv_w, conv_b, 1, 2,
                                                 x, x, resP, cs2, 1);
    gcn_kernel<<<B_ * T_ * 4, 512, 0, stream>>>(x, Wc, bc, cs2, 2, g);
    conv_kernel<<<B_ * T_ * 4, 512, 0, stream>>>(g, conv_w, conv_b, 2, 4,
                                                 x, x, resP, cs0, 0);

    att_kernel<<<(B_ * N_) / 2, 192, 0, stream>>>(resP, att_Wa, att_ba, att_v,
                                                  (float*)d_out);
}